// Round 1
// baseline (71.783 us; speedup 1.0000x reference)
//
#include <hip/hip_runtime.h>

typedef __attribute__((ext_vector_type(8))) __bf16 bf16x8;
typedef __attribute__((ext_vector_type(4))) float f32x4;

#define NCHUNK 32   // 2048 / 64
#define KC 64

__device__ __forceinline__ unsigned short f2bf(float x) {
    unsigned u = __float_as_uint(x);
    u += 0x7FFFu + ((u >> 16) & 1u);   // round-to-nearest-even
    return (unsigned short)(u >> 16);
}

// ws layout (floats): dmat[4096] | Gnn[4096] | Gaa[4096] | Rn[64] | Ra[64] | Sn[64] | Sa[64]
__global__ __launch_bounds__(256) void cl_main(const float* __restrict__ feats,
                                               float* __restrict__ ws)
{
    float* dmat = ws;
    float* Gnn  = ws + 4096;
    float* Gaa  = ws + 8192;
    float* Rn   = ws + 12288;
    float* Ra   = ws + 12352;
    float* Sn   = ws + 12416;
    float* Sa   = ws + 12480;

    const int t   = blockIdx.x;          // 0..199
    const int tid = threadIdx.x;
    const int row = tid >> 2;            // 0..63 : loader row
    const int q   = tid & 3;             // 4 loader lanes per row
    const int w   = tid >> 6;            // wave id 0..3
    const int r16 = tid & 15;            // MFMA lane&15
    const int kg  = (tid & 63) >> 4;     // MFMA k-group 0..3

    __shared__ __align__(16) unsigned short lN[64][64];
    __shared__ __align__(16) unsigned short lA[64][64];
    __shared__ float n2s[64], a2s[64];

    const float* gN = feats + (size_t)row        * 409600 + (size_t)t * 2048;
    const float* gA = feats + (size_t)(64 + row) * 409600 + (size_t)t * 2048;

    float nq = 0.f, ns = 0.f, aq = 0.f, ar = 0.f, asum = 0.f;
    f32x4 accD[4], accNN[4], accAA[4];
    const f32x4 zero = {0.f, 0.f, 0.f, 0.f};
    #pragma unroll
    for (int j = 0; j < 4; ++j) { accD[j] = zero; accNN[j] = zero; accAA[j] = zero; }

    const int swz  = (row & 7) << 3;   // write-side XOR swizzle (bf16 units)
    const int rswz = (r16 & 7) << 3;   // read-side (frag rows are jt*16+r16 -> row&7 == r16&7)

    for (int c = 0; c < NCHUNK; ++c) {
        const int ko = c * KC;
        float4 rNv[4], rAv[4];
        #pragma unroll
        for (int s = 0; s < 4; ++s) {
            const int k = 4 * q + 16 * s;
            rNv[s] = *(const float4*)(gN + ko + k);
            rAv[s] = *(const float4*)(gA + ko + k);
        }
        __syncthreads();   // previous chunk's MFMA reads done
        #pragma unroll
        for (int s = 0; s < 4; ++s) {
            const int k = 4 * q + 16 * s;
            float4 vn = rNv[s], va = rAv[s];
            nq += vn.x*vn.x + vn.y*vn.y + vn.z*vn.z + vn.w*vn.w;
            ns += vn.x + vn.y + vn.z + vn.w;
            const float e = 1e-6f;
            float ax = va.x - e, ay = va.y - e, az = va.z - e, aw = va.w - e;
            aq += ax*ax + ay*ay + az*az + aw*aw;              // a2 with EPS (dist path)
            ar += va.x*va.x + va.y*va.y + va.z*va.z + va.w*va.w; // raw (da path)
            asum += va.x + va.y + va.z + va.w;
            ushort4 pn; pn.x=f2bf(vn.x); pn.y=f2bf(vn.y); pn.z=f2bf(vn.z); pn.w=f2bf(vn.w);
            ushort4 pa; pa.x=f2bf(va.x); pa.y=f2bf(va.y); pa.z=f2bf(va.z); pa.w=f2bf(va.w);
            *(ushort4*)&lN[row][k ^ swz] = pn;
            *(ushort4*)&lA[row][k ^ swz] = pa;
        }
        __syncthreads();
        #pragma unroll
        for (int ks = 0; ks < 2; ++ks) {
            const int kb = ks * 32 + kg * 8;
            bf16x8 aN = *(const bf16x8*)&lN[w*16 + r16][kb ^ rswz];
            bf16x8 aA = *(const bf16x8*)&lA[w*16 + r16][kb ^ rswz];
            #pragma unroll
            for (int jt = 0; jt < 4; ++jt) {
                bf16x8 bN = *(const bf16x8*)&lN[jt*16 + r16][kb ^ rswz];
                bf16x8 bA = *(const bf16x8*)&lA[jt*16 + r16][kb ^ rswz];
                accD[jt]  = __builtin_amdgcn_mfma_f32_16x16x32_bf16(aN, bA, accD[jt],  0, 0, 0);
                accNN[jt] = __builtin_amdgcn_mfma_f32_16x16x32_bf16(aN, bN, accNN[jt], 0, 0, 0);
                accAA[jt] = __builtin_amdgcn_mfma_f32_16x16x32_bf16(aA, bA, accAA[jt], 0, 0, 0);
            }
        }
    }

    // reduce per-(row,t) norms across the 4 loader lanes (contiguous lanes, same wave)
    nq   += __shfl_xor(nq, 1);   nq   += __shfl_xor(nq, 2);
    aq   += __shfl_xor(aq, 1);   aq   += __shfl_xor(aq, 2);
    ns   += __shfl_xor(ns, 1);   ns   += __shfl_xor(ns, 2);
    ar   += __shfl_xor(ar, 1);   ar   += __shfl_xor(ar, 2);
    asum += __shfl_xor(asum, 1); asum += __shfl_xor(asum, 2);
    if (q == 0) {
        n2s[row] = nq;
        a2s[row] = aq;
        atomicAdd(&Rn[row], nq);
        atomicAdd(&Ra[row], ar);
        atomicAdd(&Sn[row], ns);
        atomicAdd(&Sa[row], asum);
    }
    __syncthreads();

    // epilogue: hinge + scatter. C/D layout: row=(lane>>4)*4+reg, col=lane&15
    float n2v[4];
    #pragma unroll
    for (int r = 0; r < 4; ++r) n2v[r] = n2s[w*16 + kg*4 + r];
    #pragma unroll
    for (int jt = 0; jt < 4; ++jt) {
        const float a2v = a2s[jt*16 + r16];
        #pragma unroll
        for (int r = 0; r < 4; ++r) {
            const int i = w*16 + kg*4 + r;
            const int j = jt*16 + r16;
            float cross = accD[jt][r];
            float dist2 = fmaxf(n2v[r] + a2v - 2.f * cross, 0.f);
            float v = fmaxf(200.f - sqrtf(dist2), 0.f);
            atomicAdd(&dmat[i*64 + j], v * v * 0.005f);   // 1/200
            atomicAdd(&Gnn[i*64 + j], accNN[jt][r]);
            atomicAdd(&Gaa[i*64 + j], accAA[jt][r]);
        }
    }
}

__global__ __launch_bounds__(256) void cl_final(const float* __restrict__ ws,
                                                float* __restrict__ out)
{
    const float* dmat = ws;
    const float* Gnn  = ws + 4096;
    const float* Gaa  = ws + 8192;
    const float* Rn   = ws + 12288;
    const float* Ra   = ws + 12352;
    const float* Sn   = ws + 12416;
    const float* Sa   = ws + 12480;

    const int tid = threadIdx.x;
    __shared__ float wv[4];
    __shared__ int   wi[4];
    __shared__ int   sIdx;

    // argmin with first-occurrence tie-break (matches jnp.argmin)
    float bv = 3.4e38f; int bi = 1 << 30;
    for (int k = tid; k < 4096; k += 256) {
        float v = dmat[k];
        if (v < bv) { bv = v; bi = k; }
    }
    #pragma unroll
    for (int off = 32; off > 0; off >>= 1) {
        float ov = __shfl_xor(bv, off);
        int   oi = __shfl_xor(bi, off);
        if (ov < bv || (ov == bv && oi < bi)) { bv = ov; bi = oi; }
    }
    if ((tid & 63) == 0) { wv[tid >> 6] = bv; wi[tid >> 6] = bi; }
    __syncthreads();
    if (tid == 0) {
        float fv = wv[0]; int fi = wi[0];
        for (int k = 1; k < 4; ++k)
            if (wv[k] < fv || (wv[k] == fv && wi[k] < fi)) { fv = wv[k]; fi = wi[k]; }
        sIdx = fi;
    }
    __syncthreads();
    const int idx = sIdx;
    const int mn = idx >> 6;
    const int ma = idx & 63;

    if (tid < 64) {   // whole wave 0
        float tn = 0.f, ta = 0.f;
        if (tid != mn)
            tn = Rn[tid] + Rn[mn] - 2.f * Gnn[tid*64 + mn]
               + 2e-6f * (Sn[tid] - Sn[mn]) + 409600.f * 1e-12f;
        if (tid != ma)
            ta = Ra[tid] + Ra[ma] - 2.f * Gaa[tid*64 + ma]
               + 2e-6f * (Sa[tid] - Sa[ma]) + 409600.f * 1e-12f;
        float s = tn + ta;
        #pragma unroll
        for (int off = 32; off > 0; off >>= 1) s += __shfl_xor(s, off);
        if (tid == 0)
            out[0] = 0.001f * dmat[idx] + s * (1.f / 12800.f);  // /(200*64)
    }
}

extern "C" void kernel_launch(void* const* d_in, const int* in_sizes, int n_in,
                              void* d_out, int out_size, void* d_ws, size_t ws_size,
                              hipStream_t stream)
{
    const float* feats = (const float*)d_in[0];
    float* out = (float*)d_out;
    float* ws  = (float*)d_ws;

    hipMemsetAsync(d_ws, 0, 12544 * sizeof(float), stream);
    cl_main<<<dim3(200), dim3(256), 0, stream>>>(feats, ws);
    cl_final<<<dim3(1), dim3(256), 0, stream>>>(ws, out);
}